// Round 1
// baseline (42323.407 us; speedup 1.0000x reference)
//
#include <hip/hip_runtime.h>
#include <hip/hip_cooperative_groups.h>
#include <cmath>

namespace cg = cooperative_groups;

#define NB 256
#define NT 256

__device__ __forceinline__ float sigf(float x) { return 1.0f / (1.0f + expf(-x)); }

// DPP row-shift-right add: lane i += lane (i-N) within 16-lane rows; after
// shr 8,4,2,1 lane 15 of each row holds the row sum (AMD-documented idiom).
template<int CTRL>
__device__ __forceinline__ float dpp_shr_add(float x) {
  int t = __builtin_amdgcn_update_dpp(0, __float_as_int(x), CTRL, 0xf, 0xf, true);
  return x + __int_as_float(t);
}

// ---- agent-scope coherent accessors (sc1: write-through / L2-bypassing) ----
// All cross-block-communicated data (h, argmax partials, barrier words) goes
// through these, so the grid barrier needs NO buffer_wbl2/buffer_inv and the
// read-only weights stay L2-resident across all 649 steps.
__device__ __forceinline__ float2 ald2(const float* p) {
  unsigned long long v = __hip_atomic_load((unsigned long long*)p,
      __ATOMIC_RELAXED, __HIP_MEMORY_SCOPE_AGENT);
  union { unsigned long long u; float2 f; } c; c.u = v; return c.f;
}
__device__ __forceinline__ void astf(float* p, float v) {
  __hip_atomic_store(p, v, __ATOMIC_RELAXED, __HIP_MEMORY_SCOPE_AGENT);
}
// pack (value, idx) so integer max == (larger value, then SMALLER idx) [first-max]
__device__ __forceinline__ unsigned long long packkey(float v, int idx) {
  unsigned int b = __float_as_uint(v);
  b ^= (unsigned int)((int)b >> 31) | 0x80000000u;   // orderable float bits
  return ((unsigned long long)b << 32)
       | (unsigned long long)(0xFFFFFFFFu - (unsigned int)idx);
}
__device__ __forceinline__ int unpackidx(unsigned long long pk) {
  return (int)(0xFFFFFFFFu - (unsigned int)(pk & 0xFFFFFFFFull));
}

// Relaxed monotonic grid barrier: arrival fetch_add + flag spin, agent scope.
// Correctness relies on (a) every cross-block store being sc1 (write-through to
// the coherence point), (b) every cross-block load being sc1 (L2-bypassing, so
// no stale line can be served), (c) s_waitcnt vmcnt(0) draining wave-0's sc1
// stores before the arrival atomic. NOTE: all communicated stores (h: tid<32,
// pm: tid<16, init h: tid<32) are issued by WAVE 0 == tid0's wave, so the
// single-wave vmcnt(0) drain is sufficient. Keep it that way.
__device__ __forceinline__ void gbar(unsigned int* cnt, unsigned int* flag,
                                     unsigned int gen, int tid) {
  __syncthreads();
  if (tid == 0) {
    asm volatile("s_waitcnt vmcnt(0)" ::: "memory");
    unsigned int old = __hip_atomic_fetch_add(cnt, 1u, __ATOMIC_RELAXED,
                                              __HIP_MEMORY_SCOPE_AGENT);
    if (old == gen * NB - 1u) {
      __hip_atomic_store(flag, gen, __ATOMIC_RELAXED, __HIP_MEMORY_SCOPE_AGENT);
    } else {
      while (__hip_atomic_load(flag, __ATOMIC_RELAXED,
                               __HIP_MEMORY_SCOPE_AGENT) < gen)
        __builtin_amdgcn_s_sleep(2);
    }
    asm volatile("" ::: "memory");
  }
  __syncthreads();
}

__global__ void __launch_bounds__(NT, 2) lstm_decode(
    const float* __restrict__ ctx, const float* __restrict__ emb,
    const float* __restrict__ Wih, const float* __restrict__ Whh,
    const float* __restrict__ bih, const float* __restrict__ bhh,
    const float* __restrict__ Wout, const float* __restrict__ bout,
    const int* __restrict__ sosp, float* __restrict__ out, float* __restrict__ ws)
{
  cg::grid_group grid = cg::this_grid();
  const int tid = threadIdx.x;
  const int bk  = blockIdx.x;
  const int j0  = bk * 2;                 // this block's 2 hidden indices

  float* hbuf = ws;                                   // [2][16][512] h dbuf (sc1)
  unsigned long long* pm =
      (unsigned long long*)(ws + 2 * 16 * 512);       // [250][16] packed argmax (sc1)
  unsigned int* bar = (unsigned int*)(ws + 2 * 16 * 512 + 250 * 16 * 2);
  // bar[0]=arrival counter (monotonic), bar[1]=release flag (monotonic)

  // scratch: phase-A partials [4][64][33] (33.8KB) UNION phase-B h_lds [16][520]
  __shared__ float scratch[4 * 64 * 33];
  __shared__ float logit_lds[40 * 17];
  __shared__ float base_lds[128];         // ctx-dot + biases, per (b, g_local)
  __shared__ float gacc[128];
  __shared__ unsigned long long cpk[256];
  __shared__ int   tok_lds[16];

  // ---------------- init ----------------
  if (bk == 0 && tid == 0) {              // barrier state; published by grid.sync
    __hip_atomic_store(bar + 0, 0u, __ATOMIC_RELAXED, __HIP_MEMORY_SCOPE_AGENT);
    __hip_atomic_store(bar + 1, 0u, __ATOMIC_RELAXED, __HIP_MEMORY_SCOPE_AGENT);
  }
  if (tid < 128) {                        // base[b][gl] = b_ih+b_hh+ctx.Wih[:,:512]
    int b = tid >> 3, gl = tid & 7;
    int g = (gl >> 1) * 512 + j0 + (gl & 1);
    const float* w  = Wih + (long)g * 1024;
    const float* xc = ctx + b * 512;
    float s = bih[g] + bhh[g];
    for (int k = 0; k < 512; k += 4) {
      float4 wv = *(const float4*)(w + k);
      float4 xv = *(const float4*)(xc + k);
      s += wv.x * xv.x + wv.y * xv.y + wv.z * xv.z + wv.w * xv.w;
    }
    base_lds[b * 8 + gl] = s;
  }
  float creg = 0.0f;                      // cell state: block-private -> register
  if (tid < 32) {                         // h0 = c0 = context_vec (block's j-slice)
    int b = tid >> 1, j = j0 + (tid & 1);
    float v = ctx[b * 512 + j];
    astf(hbuf + b * 512 + j, v);
    creg = v;
  }
  if (bk < 250) {                         // out[:,0,:] = 0 (re-poisoned every call)
    int r0 = bk * 40;
    for (int o = tid; o < 640; o += NT) {
      int b = o / 40, rl = o % 40;
      out[(long)b * 6500000 + (r0 + rl)] = 0.0f;
    }
  }
  grid.sync();                            // ONLY cg sync: publishes barrier init

  unsigned int gen = 0;

  // ---------------- time loop ----------------
  for (int t = 1; t < 650; ++t) {
    const float* hprev = hbuf + ((t & 1) ^ 1) * 8192;
    float*       hcur  = hbuf + (t & 1) * 8192;

    // ---- token: final argmax reduce (redundant per block, packed-u64 max) ----
    if (t == 1) {
      if (tid < 16) tok_lds[tid] = *sosp;
      __syncthreads();
    } else {
      int s = tid >> 4, b = tid & 15;
      unsigned long long best = 0ull;
      for (int q = s; q < 250; q += 16) {
        unsigned long long pk = __hip_atomic_load(pm + q * 16 + b,
            __ATOMIC_RELAXED, __HIP_MEMORY_SCOPE_AGENT);
        if (pk > best) best = pk;
      }
      cpk[b * 16 + s] = best;
      __syncthreads();
      if (tid < 16) {
        unsigned long long b2 = 0ull;
        for (int s2 = 0; s2 < 16; ++s2) {
          unsigned long long pk = cpk[tid * 16 + s2];
          if (pk > b2) b2 = pk;
        }
        tok_lds[tid] = unpackidx(b2);
      }
      __syncthreads();
    }

    // ---- phase A: gates GEMM (16b x 8g x 1024k) + cell update ----
    {
      const int kk = tid & 63;
      const int gg = (tid >> 6) & 1;
      const int bb = tid >> 7;
      float acc[8][4];
      #pragma unroll
      for (int m = 0; m < 8; ++m)
        #pragma unroll
        for (int q = 0; q < 4; ++q) acc[m][q] = 0.0f;

      const float* xrow[8]; const float* hrow[8];
      #pragma unroll
      for (int m = 0; m < 8; ++m) {
        int b = bb * 8 + m;
        xrow[m] = emb + (long)tok_lds[b] * 512;
        hrow[m] = hprev + b * 512;
      }
      const float* wi[4]; const float* wh[4];
      #pragma unroll
      for (int q = 0; q < 4; ++q) {
        int gl = gg * 4 + q;
        int g = (gl >> 1) * 512 + j0 + (gl & 1);
        wi[q] = Wih + (long)g * 1024 + 512;   // emb-half columns
        wh[q] = Whh + (long)g * 512;
      }
      #pragma unroll
      for (int j = 0; j < 4; ++j) {           // j<2: emb half, j>=2: h half
        int off = kk * 4 + (j & 1) * 256;     // lane-contiguous float4 chunks
        float4 xv[8], wv[4];
        if (j < 2) {
          #pragma unroll
          for (int m = 0; m < 8; ++m) xv[m] = *(const float4*)(xrow[m] + off);
          #pragma unroll
          for (int q = 0; q < 4; ++q) wv[q] = *(const float4*)(wi[q] + off);
        } else {
          #pragma unroll
          for (int m = 0; m < 8; ++m) {       // h: sc1 coherent 64-bit loads
            float2 a = ald2(hrow[m] + off);
            float2 b2 = ald2(hrow[m] + off + 2);
            xv[m].x = a.x; xv[m].y = a.y; xv[m].z = b2.x; xv[m].w = b2.y;
          }
          #pragma unroll
          for (int q = 0; q < 4; ++q) wv[q] = *(const float4*)(wh[q] + off);
        }
        #pragma unroll
        for (int q = 0; q < 4; ++q)
          #pragma unroll
          for (int m = 0; m < 8; ++m)
            acc[m][q] += wv[q].x * xv[m].x + wv[q].y * xv[m].y
                       + wv[q].z * xv[m].z + wv[q].w * xv[m].w;
      }
      int tile = bb * 2 + gg;
      float* p = scratch + (tile * 64 + kk) * 33;   // stride 33: <=2-way banks
      #pragma unroll
      for (int m = 0; m < 8; ++m)
        #pragma unroll
        for (int q = 0; q < 4; ++q) p[m * 4 + q] = acc[m][q];
    }
    __syncthreads();
    if (tid < 128) {                        // k-split reduce: 64 partials/output
      int b = tid >> 3, gl = tid & 7;
      int tile = (b >> 3) * 2 + (gl >> 2);
      int a = (b & 7) * 4 + (gl & 3);
      float s = 0.0f;
      const float* p = scratch + tile * 64 * 33 + a;
      #pragma unroll 8
      for (int k = 0; k < 64; ++k) s += p[k * 33];
      gacc[b * 8 + gl] = s + base_lds[b * 8 + gl];
    }
    __syncthreads();
    if (tid < 32) {                         // LSTM cell (i,f,g,o order), c in reg
      int b = tid >> 1, jj = tid & 1, j = j0 + jj;
      float ig = gacc[b * 8 + 0 + jj];
      float fg = gacc[b * 8 + 2 + jj];
      float gv = gacc[b * 8 + 4 + jj];
      float og = gacc[b * 8 + 6 + jj];
      float cn = sigf(fg) * creg + sigf(ig) * tanhf(gv);
      float hn = sigf(og) * tanhf(cn);
      creg = cn;
      astf(hcur + b * 512 + j, hn);         // sc1 write-through broadcast
    }
    gbar(bar, bar + 1, ++gen, tid);

    // ---- phase B: logits GEMM (16b x 40r x 512k) + argmax partial ----
    if (bk < 250) {
      int r0 = bk * 40;
      for (int o = tid; o < 2048; o += NT) {          // stage h -> LDS (sc1 loads)
        int b = o >> 7, k4 = o & 127;
        const float* src = hcur + b * 512 + k4 * 4;
        float2 a = ald2(src), c2 = ald2(src + 2);
        float4 v; v.x = a.x; v.y = a.y; v.z = c2.x; v.w = c2.y;
        *(float4*)(scratch + b * 520 + k4 * 4) = v;
      }
      __syncthreads();
      const int kk = tid & 15;
      const int rr = (tid >> 4) & 7;
      const int bb = tid >> 7;
      float acc[5][8];
      #pragma unroll
      for (int i = 0; i < 5; ++i)
        #pragma unroll
        for (int m = 0; m < 8; ++m) acc[i][m] = 0.0f;
      const float* wr[5];
      #pragma unroll
      for (int i = 0; i < 5; ++i) wr[i] = Wout + (long)(r0 + rr * 5 + i) * 512;
      #pragma unroll
      for (int j = 0; j < 8; ++j) {
        int k = kk * 4 + j * 64;              // interleaved: 2-way LDS aliasing only
        float4 hv[8];
        #pragma unroll
        for (int m = 0; m < 8; ++m)
          hv[m] = *(const float4*)(scratch + (bb * 8 + m) * 520 + k);
        float4 wv[5];
        #pragma unroll
        for (int i = 0; i < 5; ++i) wv[i] = *(const float4*)(wr[i] + k);
        #pragma unroll
        for (int i = 0; i < 5; ++i)
          #pragma unroll
          for (int m = 0; m < 8; ++m)
            acc[i][m] += wv[i].x * hv[m].x + wv[i].y * hv[m].y
                       + wv[i].z * hv[m].z + wv[i].w * hv[m].w;
      }
      #pragma unroll
      for (int i = 0; i < 5; ++i)             // DPP reduce over 16 kk-lanes
        #pragma unroll
        for (int m = 0; m < 8; ++m) {
          float x = acc[i][m];
          x = dpp_shr_add<0x118>(x);
          x = dpp_shr_add<0x114>(x);
          x = dpp_shr_add<0x112>(x);
          x = dpp_shr_add<0x111>(x);
          acc[i][m] = x;
        }
      if (kk == 15) {
        #pragma unroll
        for (int i = 0; i < 5; ++i) {
          int rl = rr * 5 + i;
          float bo = bout[r0 + rl];
          #pragma unroll
          for (int m = 0; m < 8; ++m)
            logit_lds[rl * 17 + bb * 8 + m] = acc[i][m] + bo;
        }
      }
      __syncthreads();
      for (int o = tid; o < 640; o += NT) {   // write logits (r-contiguous)
        int b = o / 40, rl = o % 40;
        out[(long)b * 6500000 + (long)t * 10000 + r0 + rl] = logit_lds[rl * 17 + b];
      }
      if (tid < 16) {                         // block-local argmax (first-max, packed)
        unsigned long long best = 0ull;
        for (int rl = 0; rl < 40; ++rl) {
          float v = logit_lds[rl * 17 + tid];
          unsigned long long pk = packkey(v, r0 + rl);
          if (pk > best) best = pk;
        }
        __hip_atomic_store(pm + bk * 16 + tid, best, __ATOMIC_RELAXED,
                           __HIP_MEMORY_SCOPE_AGENT);
      }
    }
    gbar(bar, bar + 1, ++gen, tid);
  }
}

extern "C" void kernel_launch(void* const* d_in, const int* in_sizes, int n_in,
                              void* d_out, int out_size, void* d_ws, size_t ws_size,
                              hipStream_t stream) {
  const float* ctx  = (const float*)d_in[0];
  const float* emb  = (const float*)d_in[1];
  const float* Wih  = (const float*)d_in[2];
  const float* Whh  = (const float*)d_in[3];
  const float* bih  = (const float*)d_in[4];
  const float* bhh  = (const float*)d_in[5];
  const float* Wout = (const float*)d_in[6];
  const float* bout = (const float*)d_in[7];
  const int*   sos  = (const int*)d_in[8];
  float* out = (float*)d_out;
  float* ws  = (float*)d_ws;
  void* args[] = { &ctx, &emb, &Wih, &Whh, &bih, &bhh, &Wout, &bout, &sos, &out, &ws };
  hipLaunchCooperativeKernel((void*)lstm_decode, dim3(NB), dim3(NT), args, 0, stream);
}